// Round 8
// baseline (643.737 us; speedup 1.0000x reference)
//
#include <hip/hip_runtime.h>

typedef __attribute__((ext_vector_type(8))) short bf16x8;
typedef __attribute__((ext_vector_type(4))) float f32x4;
typedef __attribute__((ext_vector_type(2))) unsigned int u32x2;
typedef __attribute__((ext_vector_type(4))) unsigned int u32x4;

#define MFMA16(a,b,c) __builtin_amdgcn_mfma_f32_16x16x32_bf16((a),(b),(c),0,0,0)

__device__ __forceinline__ unsigned short f2bf(float f){
  union { float f; unsigned u; } v; v.f = f;
  unsigned u = v.u;
  u += 0x7fffu + ((u >> 16) & 1u);
  return (unsigned short)(u >> 16);
}
__device__ __forceinline__ float bf2f(unsigned short h){
  union { unsigned u; float f; } v; v.u = (unsigned)h << 16;
  return v.f;
}
__device__ __forceinline__ unsigned pack2(float a, float b){
  return (unsigned)f2bf(a) | ((unsigned)f2bf(b) << 16);
}
__device__ __forceinline__ float rb(float a, float b){ float v = a + b; return v > 0.f ? v : 0.f; }
__device__ __forceinline__ bf16x8 ld16u(const unsigned short* p){ return *reinterpret_cast<const bf16x8*>(p); }

// ---------------- weight repack: [CO][CI][KH][KW] f32 -> [kb][co][k&31] bf16, k=(dh*KW+dw)*CI+ci
__global__ void pack_w(const float* __restrict__ w, unsigned short* __restrict__ dst,
                       int CO, int CI, int KH, int KW){
  int K = CI * KH * KW;
  int total = CO * K;
  for (int e = blockIdx.x * blockDim.x + threadIdx.x; e < total; e += gridDim.x * blockDim.x){
    int co = e / K, k = e - co * K;
    int dhw = k / CI, ci = k - dhw * CI;
    int dh = dhw / KW, dw = dhw - dh * KW;
    dst[((k >> 5) * CO + co) * 32 + (k & 31)] = f2bf(w[((co * CI + ci) * KH + dh) * KW + dw]);
  }
}

// conv1a hi/lo split pack: A[k] = k<9: wh[k] ; k<18: wh[k-9] ; k<27: wl[k-18] ; else 0
// pairs with B = [xh(9), xl(9), xh(9)] so dot = x*w - xl*wl  (~f32 exact)
__global__ void pack_w1a(const float* __restrict__ w, unsigned short* __restrict__ dst){
  int e = blockIdx.x * 256 + threadIdx.x;
  if (e >= 1024) return;
  int co = e >> 5, k = e & 31;
  unsigned short v = 0;
  if (k < 27){
    int j = k < 18 ? (k < 9 ? k : k - 9) : k - 18;
    float wv = w[co * 9 + j];
    unsigned short hi = f2bf(wv);
    v = (k < 18) ? hi : f2bf(wv - bf2f(hi));
  }
  dst[co * 32 + k] = v;
}

// stage1 LDS tile helpers: tile layout byte = ((r*4 + cq)*17 + c)*16, r < 34, cq = channel quad 0..3
__device__ __forceinline__ bf16x8 t1_ld(const unsigned short* buf, int r, int kq, int c){
  return *reinterpret_cast<const bf16x8*>(buf + ((r*4 + kq)*17 + c)*8);
}
// full store (both co tiles) — used by conv1a
__device__ __forceinline__ void t1_st(unsigned short* buf, int r, int px, int kq,
    const f32x4& a0, const f32x4& a1, const float* b0, const float* b1, bool valid){
  int q0 = kq >> 1, half = kq & 1;
  unsigned short* p = buf + ((r*4 + q0)*17 + px + 1)*8 + half*4;
  u32x2 s0, s1;
  s0.x = 0u; s0.y = 0u; s1.x = 0u; s1.y = 0u;
  if (valid){
    s0.x = pack2(rb(a0[0],b0[0]), rb(a0[1],b0[1]));
    s0.y = pack2(rb(a0[2],b0[2]), rb(a0[3],b0[3]));
    s1.x = pack2(rb(a1[0],b1[0]), rb(a1[1],b1[1]));
    s1.y = pack2(rb(a1[2],b1[2]), rb(a1[3],b1[3]));
  }
  *reinterpret_cast<u32x2*>(p) = s0;
  *reinterpret_cast<u32x2*>(p + 272) = s1;   // +2 quad-rows (co tile1)
}
// half store (one co tile ct) — used by s1_conv
__device__ __forceinline__ void t1_sth(unsigned short* buf, int r, int px, int kq, int ct,
    const f32x4& a, const float* b, bool valid){
  int q0 = kq >> 1, half = kq & 1;
  unsigned short* p = buf + ((r*4 + ct*2 + q0)*17 + px + 1)*8 + half*4;
  u32x2 s0; s0.x = 0u; s0.y = 0u;
  if (valid){
    s0.x = pack2(rb(a[0],b[0]), rb(a[1],b[1]));
    s0.y = pack2(rb(a[2],b[2]), rb(a[3],b[3]));
  }
  *reinterpret_cast<u32x2*>(p) = s0;
}

// one 32->32 pad-1 conv layer on stage1 LDS tiles.
// 8 waves = 2 co-tiles (ct) x 4 row-groups (rg): w[9] = 36 VGPRs/wave, ring 36 -> fits 128 cap
__device__ __forceinline__ void s1_conv(const unsigned short* src, unsigned short* dst,
    const unsigned short* __restrict__ wp, const float* __restrict__ bias,
    int base, int ROW0, int NROWS, int wid, int r16, int kq, int px){
  int ct = wid & 1, rg = wid >> 1;
  bf16x8 w[9];
#pragma unroll
  for (int kb = 0; kb < 9; ++kb)
    w[kb] = ld16u(wp + (kb*32 + ct*16 + r16)*32 + kq*8);
  float b[4];
#pragma unroll
  for (int r = 0; r < 4; ++r) b[r] = bias[ct*16 + kq*4 + r];
  int qn = NROWS >> 2, rem = NROWS & 3;
  int r0 = ROW0 + rg*qn + (rg < rem ? rg : rem);
  int len = qn + (rg < rem ? 1 : 0);          // <= 8
  bf16x8 f[3][3];
#pragma unroll
  for (int dw = 0; dw < 3; ++dw){
    f[0][dw] = t1_ld(src, r0 - 1, kq, px + dw);
    f[1][dw] = t1_ld(src, r0,     kq, px + dw);
  }
#pragma unroll
  for (int i = 0; i < 8; ++i){
    if (i < len){
      int r = r0 + i;
      const int sA = i % 3, sB = (i+1) % 3, sC = (i+2) % 3;
#pragma unroll
      for (int dw = 0; dw < 3; ++dw) f[sC][dw] = t1_ld(src, r + 1, kq, px + dw);
      f32x4 a = {0,0,0,0};
#pragma unroll
      for (int dw = 0; dw < 3; ++dw) a = MFMA16(w[dw],   f[sA][dw], a);
#pragma unroll
      for (int dw = 0; dw < 3; ++dw) a = MFMA16(w[3+dw], f[sB][dw], a);
#pragma unroll
      for (int dw = 0; dw < 3; ++dw) a = MFMA16(w[6+dw], f[sC][dw], a);
      t1_sth(dst, r, px, kq, ct, a, b, (unsigned)(base + r) < 104u);
    }
  }
}

// ---------------- megafused: x -> conv1a..1d -> pool1 -> conv2a -> conv2b -> pool2 -> P2
__global__ __launch_bounds__(512)
__attribute__((amdgpu_waves_per_eu(2, 2)))
void fused_k(
    const float* __restrict__ x,
    const unsigned short* __restrict__ wp1a, const float* __restrict__ b1a,
    const unsigned short* __restrict__ wp1b, const float* __restrict__ b1b,
    const unsigned short* __restrict__ wp1c, const float* __restrict__ b1c,
    const unsigned short* __restrict__ wp1d, const float* __restrict__ b1d,
    const unsigned short* __restrict__ wp2a, const float* __restrict__ b2a,
    const unsigned short* __restrict__ wp2b, const float* __restrict__ b2b,
    unsigned short* __restrict__ P2g)
{
  __shared__ __align__(16) char smem[133120];
  unsigned short* s_p1 = (unsigned short*)smem;                 // 49920 B
  unsigned short* bufA = (unsigned short*)(smem + 49920);       // 36992 B
  unsigned short* bufB = (unsigned short*)(smem + 86912);       // 36992 B
  float*          xsf  = (float*)(smem + 123904);               // 2516 B
  unsigned short* h2a  = (unsigned short*)(smem + 49920);       // 83200 B (overlays stage1 bufs)

  const int tid = threadIdx.x;
  const int lane = tid & 63, wid = tid >> 6;
  const int r16 = lane & 15, kq = lane >> 4;
  const int s = blockIdx.x;
  const int bb = s >> 9, tc = s & 511;

  // zero w-pad columns (pix 0 and 16) of bufA/bufB once
  for (int e = tid; e < 544; e += 512){
    int bsel = e & 1, idx = e >> 1;
    int col = idx & 1, rowq = idx >> 1;            // rowq < 136 = 34*4
    unsigned short* bp = bsel ? bufB : bufA;
    u32x4 z = {0u,0u,0u,0u};
    *reinterpret_cast<u32x4*>(bp + (rowq*17 + col*16)*8) = z;
  }

  const int px15 = r16 < 15 ? r16 : 14;

  // conv1a weights: hi/lo split fragments (K=27 of 32); live set small (~60) so keep both tiles
  bf16x8 wa0 = ld16u(wp1a + r16*32 + kq*8);
  bf16x8 wa1 = ld16u(wp1a + (16 + r16)*32 + kq*8);
  float ba0[4], ba1[4];
#pragma unroll
  for (int r = 0; r < 4; ++r){ ba0[r] = b1a[kq*4 + r]; ba1[r] = b1a[16 + kq*4 + r]; }

  // ---------- stage 1: 4 slabs of 26 conv1d-rows ----------
  for (int j = 0; j < 4; ++j){
    int base = 26*j - 4;                           // buffer row r <-> image row h = base + r
    for (int e = tid; e < 578; e += 512){          // x slab -> xs[c][ri], c: image col -1..15
      int ri = e % 34, c = e / 34;
      int h = base + ri, ttx = tc - 8 + c;
      float v = 0.f;
      // image cols -1 (c=0) and 15 (c=16) are conv1a's ZERO padding, not x data!
      if ((unsigned)(c - 1) < 15u && (unsigned)h < 104u && (unsigned)ttx < 512u)
        v = x[((size_t)bb*512 + ttx)*104 + h];
      xsf[c*37 + ri] = v;
    }
    __syncthreads();
    // conv1a (1->32) as hi/lo MFMA (x and w both split; ~f32 exact): rows 1..32 -> bufA
    {
      int r0 = 1 + wid*4;
      float v[3][3];
#pragma unroll
      for (int dw = 0; dw < 3; ++dw){
        v[0][dw] = xsf[(px15+dw)*37 + r0 - 1];
        v[1][dw] = xsf[(px15+dw)*37 + r0];
      }
#pragma unroll
      for (int i = 0; i < 4; ++i){
        int r = r0 + i;
        const int sA = i % 3, sB = (i+1) % 3, sC = (i+2) % 3;
#pragma unroll
        for (int dw = 0; dw < 3; ++dw) v[sC][dw] = xsf[(px15+dw)*37 + r + 1];
        float q[9] = { v[sA][0], v[sA][1], v[sA][2],
                       v[sB][0], v[sB][1], v[sB][2],
                       v[sC][0], v[sC][1], v[sC][2] };
        unsigned short h[9], l[9];
#pragma unroll
        for (int t = 0; t < 9; ++t){
          h[t] = f2bf(q[t]);
          l[t] = f2bf(q[t] - bf2f(h[t]));
        }
        // B = [xh(9), xl(9), xh(9), 0...] split across kq
        u32x4 tw = {0u,0u,0u,0u};
        if (kq == 0){
          tw.x = (unsigned)h[0] | ((unsigned)h[1] << 16);
          tw.y = (unsigned)h[2] | ((unsigned)h[3] << 16);
          tw.z = (unsigned)h[4] | ((unsigned)h[5] << 16);
          tw.w = (unsigned)h[6] | ((unsigned)h[7] << 16);
        } else if (kq == 1){
          tw.x = (unsigned)h[8] | ((unsigned)l[0] << 16);
          tw.y = (unsigned)l[1] | ((unsigned)l[2] << 16);
          tw.z = (unsigned)l[3] | ((unsigned)l[4] << 16);
          tw.w = (unsigned)l[5] | ((unsigned)l[6] << 16);
        } else if (kq == 2){
          tw.x = (unsigned)l[7] | ((unsigned)l[8] << 16);
          tw.y = (unsigned)h[0] | ((unsigned)h[1] << 16);
          tw.z = (unsigned)h[2] | ((unsigned)h[3] << 16);
          tw.w = (unsigned)h[4] | ((unsigned)h[5] << 16);
        } else {
          tw.x = (unsigned)h[6] | ((unsigned)h[7] << 16);
          tw.y = (unsigned)h[8];
        }
        bf16x8 bf = *reinterpret_cast<bf16x8*>(&tw);
        f32x4 z = {0,0,0,0};
        f32x4 a0 = MFMA16(wa0, bf, z);
        f32x4 a1 = MFMA16(wa1, bf, z);
        t1_st(bufA, r, px15, kq, a0, a1, ba0, ba1, (unsigned)(base + r) < 104u);
      }
    }
    __syncthreads();
    s1_conv(bufA, bufB, wp1b, b1b, base, 2, 30, wid, r16, kq, px15);
    __syncthreads();
    s1_conv(bufB, bufA, wp1c, b1c, base, 3, 28, wid, r16, kq, px15);
    __syncthreads();
    s1_conv(bufA, bufB, wp1d, b1d, base, 4, 26, wid, r16, kq, px15);
    __syncthreads();
    // maxpool(2,1): bufB rows 4..29 -> s_p1 rows 13j..13j+12
    for (int e = tid; e < 780; e += 512){
      int cg = e & 3, w = (e >> 2) % 15, pr = e / 60;
      const unsigned short* pA = bufB + (((4 + 2*pr)*4 + cg)*17 + w + 1)*8;
      bf16x8 va = *reinterpret_cast<const bf16x8*>(pA);
      bf16x8 vb = *reinterpret_cast<const bf16x8*>(pA + 544);
      bf16x8 rv;
#pragma unroll
      for (int q = 0; q < 8; ++q){
        unsigned short ua = (unsigned short)va[q], ub = (unsigned short)vb[q];
        rv[q] = (short)(ua > ub ? ua : ub);          // relu'd bf16 >= 0: bit max == fp max
      }
      *reinterpret_cast<bf16x8*>(s_p1 + (((13*j + pr)*4 + cg)*15 + w)*8) = rv;
    }
    __syncthreads();
  }

  // ---------- conv2a: 32->64, pad0, s_p1 (52x15) -> h2a (50x13) ----------
  // 8 waves = 4 co-tiles (ct) x 2 row-halves (rh, 25 rows each): 36 weight VGPRs/wave
  {
    int ct = wid & 3, rh = wid >> 2;
    bf16x8 w2[9];
#pragma unroll
    for (int kb = 0; kb < 9; ++kb)
      w2[kb] = ld16u(wp2a + (kb*64 + ct*16 + r16)*32 + kq*8);
    float bs[4];
#pragma unroll
    for (int r = 0; r < 4; ++r) bs[r] = b2a[ct*16 + kq*4 + r];
    int px = r16 < 13 ? r16 : 12;
    int r0 = rh * 25;
    bf16x8 f[3][3];
#pragma unroll
    for (int dw = 0; dw < 3; ++dw){
      f[0][dw] = *reinterpret_cast<const bf16x8*>(s_p1 + ((r0*4 + kq)*15 + px + dw)*8);
      f[1][dw] = *reinterpret_cast<const bf16x8*>(s_p1 + (((r0+1)*4 + kq)*15 + px + dw)*8);
    }
    int q0 = kq >> 1, half = kq & 1;
#pragma unroll
    for (int i = 0; i < 25; ++i){
      int r = r0 + i;
      const int sA = i % 3, sB = (i+1) % 3, sC = (i+2) % 3;
#pragma unroll
      for (int dw = 0; dw < 3; ++dw)
        f[sC][dw] = *reinterpret_cast<const bf16x8*>(s_p1 + (((r+2)*4 + kq)*15 + px + dw)*8);
      f32x4 a = {0,0,0,0};
#pragma unroll
      for (int dw = 0; dw < 3; ++dw) a = MFMA16(w2[dw],   f[sA][dw], a);
#pragma unroll
      for (int dw = 0; dw < 3; ++dw) a = MFMA16(w2[3+dw], f[sB][dw], a);
#pragma unroll
      for (int dw = 0; dw < 3; ++dw) a = MFMA16(w2[6+dw], f[sC][dw], a);
      u32x2 sv;
      sv.x = pack2(rb(a[0],bs[0]), rb(a[1],bs[1]));
      sv.y = pack2(rb(a[2],bs[2]), rb(a[3],bs[3]));
      *reinterpret_cast<u32x2*>(h2a + ((r*8 + ct*2 + q0)*13 + px)*8 + half*4) = sv;
    }
  }
  __syncthreads();

  // ---------- conv2b (64->64, pad0, 50x13 -> 48x11) + maxpool(2,1) -> P2 global ----------
  // 8 waves = 4 co-tiles (ct) x 2 row-groups (rg, 24 rows); NO f-ring: 18 fresh ds_reads/row
  {
    int ct = wid & 3, rg = wid >> 2;
    bf16x8 wt[18];
#pragma unroll
    for (int kb = 0; kb < 18; ++kb)
      wt[kb] = ld16u(wp2b + (kb*64 + ct*16 + r16)*32 + kq*8);
    float bt[4];
#pragma unroll
    for (int r = 0; r < 4; ++r) bt[r] = b2b[ct*16 + kq*4 + r];
    int px = r16 < 11 ? r16 : 10;
    int r0 = rg * 24;
    float pv[4];
#pragma unroll
    for (int r4 = 0; r4 < 4; ++r4) pv[r4] = 0.f;
#pragma unroll 2
    for (int i = 0; i < 24; ++i){
      int r = r0 + i;
      f32x4 a0 = {0,0,0,0};
#pragma unroll
      for (int dh = 0; dh < 3; ++dh)
#pragma unroll
        for (int dw = 0; dw < 3; ++dw)
#pragma unroll
          for (int hf = 0; hf < 2; ++hf){
            bf16x8 bf = *reinterpret_cast<const bf16x8*>(h2a + (((r+dh)*8 + hf*4 + kq)*13 + px + dw)*8);
            a0 = MFMA16(wt[(dh*3+dw)*2 + hf], bf, a0);
          }
      if ((i & 1) == 0){
#pragma unroll
        for (int r4 = 0; r4 < 4; ++r4) pv[r4] = rb(a0[r4], bt[r4]);
      } else {
        if (r16 < 11){
          int pp = (r >> 1)*11 + px;
          unsigned short* dp = P2g + (size_t)s*16896 + pp*64 + ct*16 + kq*4;
          u32x2 qv;
          float c0, c1;
          c0 = rb(a0[0], bt[0]); c1 = rb(a0[1], bt[1]);
          qv.x = pack2(pv[0] > c0 ? pv[0] : c0, pv[1] > c1 ? pv[1] : c1);
          c0 = rb(a0[2], bt[2]); c1 = rb(a0[3], bt[3]);
          qv.y = pack2(pv[2] > c0 ? pv[2] : c0, pv[3] > c1 ? pv[3] : c1);
          *reinterpret_cast<u32x2*>(dp) = qv;
        }
      }
    }
  }
}

// ---------------- conv3 (64->128, 12x9) + relu + sum(13x3) + 1x1 head, 4 samples/block
// waves = (tg: co-half) x (sg: sample-pair) x (par: kb parity); par-reduction via LDS
__global__ __launch_bounds__(512)
__attribute__((amdgpu_waves_per_eu(2, 2)))
void conv3_k(const unsigned short* __restrict__ p2,
      const unsigned short* __restrict__ wp3, const float* __restrict__ b3,
      const float* __restrict__ wl, const float* __restrict__ bl,
      float* __restrict__ out)
{
  __shared__ __align__(16) char smem[137216];
  char* lds = smem;                                   // 4 * 33792 staged P2 (swizzled); later reduction
  float* sbuf = (float*)(smem + 135168);              // 4 * 128 floats

  const int tid = threadIdx.x;
  const int lane = tid & 63, wid = tid >> 6;
  const int r16 = lane & 15, kq = lane >> 4;
  const int blk = blockIdx.x;

  // stage 4 samples, XOR-swizzled channel-quads
  const unsigned short* src = p2 + (size_t)blk * 4 * 16896;
  for (int c = tid; c < 8448; c += 512){
    int e = c * 8;
    int sl = e / 16896; int er = e - sl * 16896;
    int pix = er >> 6; int cc = (er >> 3) & 7;
    int dstb = sl * 33792 + pix * 128 + ((cc ^ (pix & 7)) << 4);
    *reinterpret_cast<bf16x8*>(lds + dstb) = ld16u(src + e);
  }
  __syncthreads();

  const int tg = wid & 1, sg = (wid >> 1) & 1, par = wid >> 2;
  int ipb[3]; int vm[3];
#pragma unroll
  for (int m = 0; m < 3; ++m){
    int p = m*16 + r16;
    vm[m] = (p < 39);
    int pc = p < 39 ? p : 38;
    int h = pc / 3, w = pc - h*3;
    ipb[m] = h*11 + w;
  }
  f32x4 acc[3][2][4];
#pragma unroll
  for (int m = 0; m < 3; ++m)
#pragma unroll
    for (int ss2 = 0; ss2 < 2; ++ss2)
#pragma unroll
      for (int t4 = 0; t4 < 4; ++t4) acc[m][ss2][t4] = (f32x4){0,0,0,0};

  const unsigned short* wb = wp3 + (size_t)par*4096 + tg*2048 + r16*32 + kq*8;
  bf16x8 wc[4];
#pragma unroll
  for (int t4 = 0; t4 < 4; ++t4) wc[t4] = ld16u(wb + t4*512);
  const int cc0 = par*4 + kq;
  int dh = 0, dw = 0;
  for (int k = 0; k < 108; ++k){
    bf16x8 wn[4];
    if (k < 107){
      const unsigned short* wb2 = wb + (size_t)(k+1)*8192;
#pragma unroll
      for (int t4 = 0; t4 < 4; ++t4) wn[t4] = ld16u(wb2 + t4*512);
    } else {
#pragma unroll
      for (int t4 = 0; t4 < 4; ++t4) wn[t4] = wc[t4];
    }
    int d = dh*11 + dw;
#pragma unroll
    for (int m = 0; m < 3; ++m){
      int ip = ipb[m] + d;
      int bo = ip*128 + ((cc0 ^ (ip & 7)) << 4);
#pragma unroll
      for (int ss2 = 0; ss2 < 2; ++ss2){
        bf16x8 bf = *reinterpret_cast<const bf16x8*>(lds + (sg*2 + ss2)*33792 + bo);
#pragma unroll
        for (int t4 = 0; t4 < 4; ++t4) acc[m][ss2][t4] = MFMA16(wc[t4], bf, acc[m][ss2][t4]);
      }
    }
#pragma unroll
    for (int t4 = 0; t4 < 4; ++t4) wc[t4] = wn[t4];
    if (++dw == 9){ dw = 0; ++dh; }
  }
  __syncthreads();

  f32x4* red = (f32x4*)lds;   // 4 waves * 24 * 64 * 16B = 98304 <= 135168
  if (par == 1){
#pragma unroll
    for (int m = 0; m < 3; ++m)
#pragma unroll
      for (int ss2 = 0; ss2 < 2; ++ss2)
#pragma unroll
        for (int t4 = 0; t4 < 4; ++t4)
          red[(((tg*2 + sg)*6 + m*2 + ss2)*4 + t4)*64 + lane] = acc[m][ss2][t4];
  }
  __syncthreads();
  if (par == 0){
    float sv[2][4][4];
#pragma unroll
    for (int m = 0; m < 3; ++m)
#pragma unroll
      for (int ss2 = 0; ss2 < 2; ++ss2)
#pragma unroll
        for (int t4 = 0; t4 < 4; ++t4){
          f32x4 o = red[(((tg*2 + sg)*6 + m*2 + ss2)*4 + t4)*64 + lane];
#pragma unroll
          for (int r = 0; r < 4; ++r){
            float v = acc[m][ss2][t4][r] + o[r] + b3[(tg*4 + t4)*16 + kq*4 + r];
            v = v > 0.f ? v : 0.f;
            v = vm[m] ? v : 0.f;
            if (m == 0) sv[ss2][t4][r] = v; else sv[ss2][t4][r] += v;
          }
        }
#pragma unroll
    for (int off = 1; off < 16; off <<= 1)
#pragma unroll
      for (int ss2 = 0; ss2 < 2; ++ss2)
#pragma unroll
        for (int t4 = 0; t4 < 4; ++t4)
#pragma unroll
          for (int r = 0; r < 4; ++r) sv[ss2][t4][r] += __shfl_xor(sv[ss2][t4][r], off, 16);
    if (r16 == 0){
#pragma unroll
      for (int ss2 = 0; ss2 < 2; ++ss2)
#pragma unroll
        for (int t4 = 0; t4 < 4; ++t4)
#pragma unroll
          for (int r = 0; r < 4; ++r)
            sbuf[(sg*2 + ss2)*128 + (tg*4 + t4)*16 + kq*4 + r] = sv[ss2][t4][r];
    }
  }
  __syncthreads();
  if (tid < 100){
    int ss = tid / 25, o = tid - ss*25;
    float a = 0.f;
    for (int c = 0; c < 128; ++c) a += wl[o*128 + c] * sbuf[ss*128 + c];
    out[(size_t)(blk*4 + ss)*25 + o] = a * (1.f/39.f) + bl[o];
  }
}

extern "C" void kernel_launch(void* const* d_in, const int* in_sizes, int n_in,
                              void* d_out, int out_size, void* d_ws, size_t ws_size,
                              hipStream_t stream){
  const float* x   = (const float*)d_in[0];
  const float* w1a = (const float*)d_in[1];  const float* b1a = (const float*)d_in[2];
  const float* w1b = (const float*)d_in[3];  const float* b1b = (const float*)d_in[4];
  const float* w1c = (const float*)d_in[5];  const float* b1c = (const float*)d_in[6];
  const float* w1d = (const float*)d_in[7];  const float* b1d = (const float*)d_in[8];
  const float* w2a = (const float*)d_in[9];  const float* b2a = (const float*)d_in[10];
  const float* w2b = (const float*)d_in[11]; const float* b2b = (const float*)d_in[12];
  const float* w3  = (const float*)d_in[13]; const float* b3  = (const float*)d_in[14];
  const float* wl  = (const float*)d_in[15]; const float* bl  = (const float*)d_in[16];
  float* out = (float*)d_out;

  unsigned short* ws0  = (unsigned short*)d_ws;
  unsigned short* wp1a = ws0;                 // 1024 (hi/lo split)
  unsigned short* wp1b = wp1a + 1024;         // 9216
  unsigned short* wp1c = wp1b + 9216;         // 9216
  unsigned short* wp1d = wp1c + 9216;         // 9216
  unsigned short* wp2a = wp1d + 9216;         // 18432
  unsigned short* wp2b = wp2a + 18432;        // 36864
  unsigned short* wp3  = wp2b + 36864;        // 884736
  unsigned short* P2   = wp3 + 884736;        // 2048 * 16896

  pack_w1a<<<4, 256, 0, stream>>>(w1a, wp1a);
  pack_w<<<36,   256, 0, stream>>>(w1b, wp1b, 32, 32, 3, 3);
  pack_w<<<36,   256, 0, stream>>>(w1c, wp1c, 32, 32, 3, 3);
  pack_w<<<36,   256, 0, stream>>>(w1d, wp1d, 32, 32, 3, 3);
  pack_w<<<72,   256, 0, stream>>>(w2a, wp2a, 64, 32, 3, 3);
  pack_w<<<144,  256, 0, stream>>>(w2b, wp2b, 64, 64, 3, 3);
  pack_w<<<3456, 256, 0, stream>>>(w3,  wp3, 128, 64, 12, 9);

  fused_k<<<2048, 512, 0, stream>>>(x, wp1a, b1a, wp1b, b1b, wp1c, b1c, wp1d, b1d,
                                    wp2a, b2a, wp2b, b2b, P2);
  conv3_k<<<512, 512, 0, stream>>>(P2, wp3, b3, wl, bl, out);
}

// Round 9
// 642.866 us; speedup vs baseline: 1.0014x; 1.0014x over previous
//
#include <hip/hip_runtime.h>

typedef __attribute__((ext_vector_type(8))) short bf16x8;
typedef __attribute__((ext_vector_type(4))) float f32x4;
typedef __attribute__((ext_vector_type(2))) unsigned int u32x2;
typedef __attribute__((ext_vector_type(4))) unsigned int u32x4;

#define MFMA16(a,b,c) __builtin_amdgcn_mfma_f32_16x16x32_bf16((a),(b),(c),0,0,0)

__device__ __forceinline__ unsigned short f2bf(float f){
  union { float f; unsigned u; } v; v.f = f;
  unsigned u = v.u;
  u += 0x7fffu + ((u >> 16) & 1u);
  return (unsigned short)(u >> 16);
}
__device__ __forceinline__ float bf2f(unsigned short h){
  union { unsigned u; float f; } v; v.u = (unsigned)h << 16;
  return v.f;
}
__device__ __forceinline__ unsigned pack2(float a, float b){
  return (unsigned)f2bf(a) | ((unsigned)f2bf(b) << 16);
}
__device__ __forceinline__ float rb(float a, float b){ float v = a + b; return v > 0.f ? v : 0.f; }
__device__ __forceinline__ bf16x8 ld16u(const unsigned short* p){ return *reinterpret_cast<const bf16x8*>(p); }

// ---------------- weight repack: [CO][CI][KH][KW] f32 -> [kb][co][k&31] bf16, k=(dh*KW+dw)*CI+ci
__global__ void pack_w(const float* __restrict__ w, unsigned short* __restrict__ dst,
                       int CO, int CI, int KH, int KW){
  int K = CI * KH * KW;
  int total = CO * K;
  for (int e = blockIdx.x * blockDim.x + threadIdx.x; e < total; e += gridDim.x * blockDim.x){
    int co = e / K, k = e - co * K;
    int dhw = k / CI, ci = k - dhw * CI;
    int dh = dhw / KW, dw = dhw - dh * KW;
    dst[((k >> 5) * CO + co) * 32 + (k & 31)] = f2bf(w[((co * CI + ci) * KH + dh) * KW + dw]);
  }
}

// conv1a hi/lo split pack: A[k] = k<9: wh[k] ; k<18: wh[k-9] ; k<27: wl[k-18] ; else 0
// pairs with B = [xh(9), xl(9), xh(9)] so dot = x*w - xl*wl  (~f32 exact)
__global__ void pack_w1a(const float* __restrict__ w, unsigned short* __restrict__ dst){
  int e = blockIdx.x * 256 + threadIdx.x;
  if (e >= 1024) return;
  int co = e >> 5, k = e & 31;
  unsigned short v = 0;
  if (k < 27){
    int j = k < 18 ? (k < 9 ? k : k - 9) : k - 18;
    float wv = w[co * 9 + j];
    unsigned short hi = f2bf(wv);
    v = (k < 18) ? hi : f2bf(wv - bf2f(hi));
  }
  dst[co * 32 + k] = v;
}

// stage1 LDS tile helpers: tile layout byte = ((r*4 + cq)*17 + c)*16, r < 34, cq = channel quad 0..3
__device__ __forceinline__ bf16x8 t1_ld(const unsigned short* buf, int r, int kq, int c){
  return *reinterpret_cast<const bf16x8*>(buf + ((r*4 + kq)*17 + c)*8);
}
// full store (both co tiles) — used by conv1a
__device__ __forceinline__ void t1_st(unsigned short* buf, int r, int px, int kq,
    const f32x4& a0, const f32x4& a1, const float* b0, const float* b1, bool valid){
  int q0 = kq >> 1, half = kq & 1;
  unsigned short* p = buf + ((r*4 + q0)*17 + px + 1)*8 + half*4;
  u32x2 s0, s1;
  s0.x = 0u; s0.y = 0u; s1.x = 0u; s1.y = 0u;
  if (valid){
    s0.x = pack2(rb(a0[0],b0[0]), rb(a0[1],b0[1]));
    s0.y = pack2(rb(a0[2],b0[2]), rb(a0[3],b0[3]));
    s1.x = pack2(rb(a1[0],b1[0]), rb(a1[1],b1[1]));
    s1.y = pack2(rb(a1[2],b1[2]), rb(a1[3],b1[3]));
  }
  *reinterpret_cast<u32x2*>(p) = s0;
  *reinterpret_cast<u32x2*>(p + 272) = s1;   // +2 quad-rows (co tile1)
}
// half store (one co tile ct) — used by s1_conv
__device__ __forceinline__ void t1_sth(unsigned short* buf, int r, int px, int kq, int ct,
    const f32x4& a, const float* b, bool valid){
  int q0 = kq >> 1, half = kq & 1;
  unsigned short* p = buf + ((r*4 + ct*2 + q0)*17 + px + 1)*8 + half*4;
  u32x2 s0; s0.x = 0u; s0.y = 0u;
  if (valid){
    s0.x = pack2(rb(a[0],b[0]), rb(a[1],b[1]));
    s0.y = pack2(rb(a[2],b[2]), rb(a[3],b[3]));
  }
  *reinterpret_cast<u32x2*>(p) = s0;
}

// one 32->32 pad-1 conv layer on stage1 LDS tiles.
// 8 waves = 2 co-tiles (ct) x 4 row-groups (rg): w[9] = 36 VGPRs/wave, ring 36 -> fits 128 cap
__device__ __forceinline__ void s1_conv(const unsigned short* src, unsigned short* dst,
    const unsigned short* __restrict__ wp, const float* __restrict__ bias,
    int base, int ROW0, int NROWS, int wid, int r16, int kq, int px){
  int ct = wid & 1, rg = wid >> 1;
  bf16x8 w[9];
#pragma unroll
  for (int kb = 0; kb < 9; ++kb)
    w[kb] = ld16u(wp + (kb*32 + ct*16 + r16)*32 + kq*8);
  float b[4];
#pragma unroll
  for (int r = 0; r < 4; ++r) b[r] = bias[ct*16 + kq*4 + r];
  int qn = NROWS >> 2, rem = NROWS & 3;
  int r0 = ROW0 + rg*qn + (rg < rem ? rg : rem);
  int len = qn + (rg < rem ? 1 : 0);          // <= 8
  bf16x8 f[3][3];
#pragma unroll
  for (int dw = 0; dw < 3; ++dw){
    f[0][dw] = t1_ld(src, r0 - 1, kq, px + dw);
    f[1][dw] = t1_ld(src, r0,     kq, px + dw);
  }
#pragma unroll
  for (int i = 0; i < 8; ++i){
    if (i < len){
      int r = r0 + i;
      const int sA = i % 3, sB = (i+1) % 3, sC = (i+2) % 3;
#pragma unroll
      for (int dw = 0; dw < 3; ++dw) f[sC][dw] = t1_ld(src, r + 1, kq, px + dw);
      f32x4 a = {0,0,0,0};
#pragma unroll
      for (int dw = 0; dw < 3; ++dw) a = MFMA16(w[dw],   f[sA][dw], a);
#pragma unroll
      for (int dw = 0; dw < 3; ++dw) a = MFMA16(w[3+dw], f[sB][dw], a);
#pragma unroll
      for (int dw = 0; dw < 3; ++dw) a = MFMA16(w[6+dw], f[sC][dw], a);
      t1_sth(dst, r, px, kq, ct, a, b, (unsigned)(base + r) < 104u);
    }
  }
}

// ---------------- megafused: x -> conv1a..1d -> pool1 -> conv2a -> conv2b -> pool2 -> P2
__global__ __launch_bounds__(512)
__attribute__((amdgpu_waves_per_eu(2, 2)))
void fused_k(
    const float* __restrict__ x,
    const unsigned short* __restrict__ wp1a, const float* __restrict__ b1a,
    const unsigned short* __restrict__ wp1b, const float* __restrict__ b1b,
    const unsigned short* __restrict__ wp1c, const float* __restrict__ b1c,
    const unsigned short* __restrict__ wp1d, const float* __restrict__ b1d,
    const unsigned short* __restrict__ wp2a, const float* __restrict__ b2a,
    const unsigned short* __restrict__ wp2b, const float* __restrict__ b2b,
    unsigned short* __restrict__ P2g)
{
  __shared__ __align__(16) char smem[133120];
  unsigned short* s_p1 = (unsigned short*)smem;                 // 49920 B
  unsigned short* bufA = (unsigned short*)(smem + 49920);       // 36992 B
  unsigned short* bufB = (unsigned short*)(smem + 86912);       // 36992 B
  float*          xsf  = (float*)(smem + 123904);               // 2516 B
  unsigned short* h2a  = (unsigned short*)(smem + 49920);       // 83200 B (overlays stage1 bufs)

  const int tid = threadIdx.x;
  const int lane = tid & 63, wid = tid >> 6;
  const int r16 = lane & 15, kq = lane >> 4;
  const int s = blockIdx.x;
  const int bb = s >> 9, tc = s & 511;

  // zero w-pad columns (pix 0 and 16) of bufA/bufB once
  for (int e = tid; e < 544; e += 512){
    int bsel = e & 1, idx = e >> 1;
    int col = idx & 1, rowq = idx >> 1;            // rowq < 136 = 34*4
    unsigned short* bp = bsel ? bufB : bufA;
    u32x4 z = {0u,0u,0u,0u};
    *reinterpret_cast<u32x4*>(bp + (rowq*17 + col*16)*8) = z;
  }

  const int px15 = r16 < 15 ? r16 : 14;

  // conv1a weights: hi/lo split fragments (K=27 of 32); live set small (~60) so keep both tiles
  bf16x8 wa0 = ld16u(wp1a + r16*32 + kq*8);
  bf16x8 wa1 = ld16u(wp1a + (16 + r16)*32 + kq*8);
  float ba0[4], ba1[4];
#pragma unroll
  for (int r = 0; r < 4; ++r){ ba0[r] = b1a[kq*4 + r]; ba1[r] = b1a[16 + kq*4 + r]; }

  // ---------- stage 1: 4 slabs of 26 conv1d-rows ----------
  for (int j = 0; j < 4; ++j){
    int base = 26*j - 4;                           // buffer row r <-> image row h = base + r
    for (int e = tid; e < 578; e += 512){          // x slab -> xs[c][ri], c: image col -1..15
      int ri = e % 34, c = e / 34;
      int h = base + ri, ttx = tc - 8 + c;
      float v = 0.f;
      // image cols -1 (c=0) and 15 (c=16) are conv1a's ZERO padding, not x data!
      if ((unsigned)(c - 1) < 15u && (unsigned)h < 104u && (unsigned)ttx < 512u)
        v = x[((size_t)bb*512 + ttx)*104 + h];
      xsf[c*37 + ri] = v;
    }
    __syncthreads();
    // conv1a (1->32) as hi/lo MFMA (x and w both split; ~f32 exact): rows 1..32 -> bufA
    {
      int r0 = 1 + wid*4;
      float v[3][3];
#pragma unroll
      for (int dw = 0; dw < 3; ++dw){
        v[0][dw] = xsf[(px15+dw)*37 + r0 - 1];
        v[1][dw] = xsf[(px15+dw)*37 + r0];
      }
#pragma unroll
      for (int i = 0; i < 4; ++i){
        int r = r0 + i;
        const int sA = i % 3, sB = (i+1) % 3, sC = (i+2) % 3;
#pragma unroll
        for (int dw = 0; dw < 3; ++dw) v[sC][dw] = xsf[(px15+dw)*37 + r + 1];
        float q[9] = { v[sA][0], v[sA][1], v[sA][2],
                       v[sB][0], v[sB][1], v[sB][2],
                       v[sC][0], v[sC][1], v[sC][2] };
        unsigned short h[9], l[9];
#pragma unroll
        for (int t = 0; t < 9; ++t){
          h[t] = f2bf(q[t]);
          l[t] = f2bf(q[t] - bf2f(h[t]));
        }
        // B = [xh(9), xl(9), xh(9), 0...] split across kq
        u32x4 tw = {0u,0u,0u,0u};
        if (kq == 0){
          tw.x = (unsigned)h[0] | ((unsigned)h[1] << 16);
          tw.y = (unsigned)h[2] | ((unsigned)h[3] << 16);
          tw.z = (unsigned)h[4] | ((unsigned)h[5] << 16);
          tw.w = (unsigned)h[6] | ((unsigned)h[7] << 16);
        } else if (kq == 1){
          tw.x = (unsigned)h[8] | ((unsigned)l[0] << 16);
          tw.y = (unsigned)l[1] | ((unsigned)l[2] << 16);
          tw.z = (unsigned)l[3] | ((unsigned)l[4] << 16);
          tw.w = (unsigned)l[5] | ((unsigned)l[6] << 16);
        } else if (kq == 2){
          tw.x = (unsigned)l[7] | ((unsigned)l[8] << 16);
          tw.y = (unsigned)h[0] | ((unsigned)h[1] << 16);
          tw.z = (unsigned)h[2] | ((unsigned)h[3] << 16);
          tw.w = (unsigned)h[4] | ((unsigned)h[5] << 16);
        } else {
          tw.x = (unsigned)h[6] | ((unsigned)h[7] << 16);
          tw.y = (unsigned)h[8];
        }
        bf16x8 bf = *reinterpret_cast<bf16x8*>(&tw);
        f32x4 z = {0,0,0,0};
        f32x4 a0 = MFMA16(wa0, bf, z);
        f32x4 a1 = MFMA16(wa1, bf, z);
        t1_st(bufA, r, px15, kq, a0, a1, ba0, ba1, (unsigned)(base + r) < 104u);
      }
    }
    __syncthreads();
    s1_conv(bufA, bufB, wp1b, b1b, base, 2, 30, wid, r16, kq, px15);
    __syncthreads();
    s1_conv(bufB, bufA, wp1c, b1c, base, 3, 28, wid, r16, kq, px15);
    __syncthreads();
    s1_conv(bufA, bufB, wp1d, b1d, base, 4, 26, wid, r16, kq, px15);
    __syncthreads();
    // maxpool(2,1): bufB rows 4..29 -> s_p1 rows 13j..13j+12
    for (int e = tid; e < 780; e += 512){
      int cg = e & 3, w = (e >> 2) % 15, pr = e / 60;
      const unsigned short* pA = bufB + (((4 + 2*pr)*4 + cg)*17 + w + 1)*8;
      bf16x8 va = *reinterpret_cast<const bf16x8*>(pA);
      bf16x8 vb = *reinterpret_cast<const bf16x8*>(pA + 544);
      bf16x8 rv;
#pragma unroll
      for (int q = 0; q < 8; ++q){
        unsigned short ua = (unsigned short)va[q], ub = (unsigned short)vb[q];
        rv[q] = (short)(ua > ub ? ua : ub);          // relu'd bf16 >= 0: bit max == fp max
      }
      *reinterpret_cast<bf16x8*>(s_p1 + (((13*j + pr)*4 + cg)*15 + w)*8) = rv;
    }
    __syncthreads();
  }

  // ---------- conv2a: 32->64, pad0, s_p1 (52x15) -> h2a (50x13) ----------
  // 8 waves = 4 co-tiles (ct) x 2 row-halves (rh, 25 rows each): 36 weight VGPRs/wave
  {
    int ct = wid & 3, rh = wid >> 2;
    bf16x8 w2[9];
#pragma unroll
    for (int kb = 0; kb < 9; ++kb)
      w2[kb] = ld16u(wp2a + (kb*64 + ct*16 + r16)*32 + kq*8);
    float bs[4];
#pragma unroll
    for (int r = 0; r < 4; ++r) bs[r] = b2a[ct*16 + kq*4 + r];
    int px = r16 < 13 ? r16 : 12;
    int r0 = rh * 25;
    bf16x8 f[3][3];
#pragma unroll
    for (int dw = 0; dw < 3; ++dw){
      f[0][dw] = *reinterpret_cast<const bf16x8*>(s_p1 + ((r0*4 + kq)*15 + px + dw)*8);
      f[1][dw] = *reinterpret_cast<const bf16x8*>(s_p1 + (((r0+1)*4 + kq)*15 + px + dw)*8);
    }
    int q0 = kq >> 1, half = kq & 1;
#pragma unroll
    for (int i = 0; i < 25; ++i){
      int r = r0 + i;
      const int sA = i % 3, sB = (i+1) % 3, sC = (i+2) % 3;
#pragma unroll
      for (int dw = 0; dw < 3; ++dw)
        f[sC][dw] = *reinterpret_cast<const bf16x8*>(s_p1 + (((r+2)*4 + kq)*15 + px + dw)*8);
      f32x4 a = {0,0,0,0};
#pragma unroll
      for (int dw = 0; dw < 3; ++dw) a = MFMA16(w2[dw],   f[sA][dw], a);
#pragma unroll
      for (int dw = 0; dw < 3; ++dw) a = MFMA16(w2[3+dw], f[sB][dw], a);
#pragma unroll
      for (int dw = 0; dw < 3; ++dw) a = MFMA16(w2[6+dw], f[sC][dw], a);
      u32x2 sv;
      sv.x = pack2(rb(a[0],bs[0]), rb(a[1],bs[1]));
      sv.y = pack2(rb(a[2],bs[2]), rb(a[3],bs[3]));
      *reinterpret_cast<u32x2*>(h2a + ((r*8 + ct*2 + q0)*13 + px)*8 + half*4) = sv;
    }
  }
  __syncthreads();

  // ---------- conv2b (64->64, pad0, 50x13 -> 48x11) + maxpool(2,1) -> P2 global ----------
  // 8 waves = 4 co-tiles (ct) x 2 row-groups (rg, 24 rows); NO f-ring: 18 fresh ds_reads/row
  {
    int ct = wid & 3, rg = wid >> 2;
    bf16x8 wt[18];
#pragma unroll
    for (int kb = 0; kb < 18; ++kb)
      wt[kb] = ld16u(wp2b + (kb*64 + ct*16 + r16)*32 + kq*8);
    float bt[4];
#pragma unroll
    for (int r = 0; r < 4; ++r) bt[r] = b2b[ct*16 + kq*4 + r];
    int px = r16 < 11 ? r16 : 10;
    int r0 = rg * 24;
    float pv[4];
#pragma unroll
    for (int r4 = 0; r4 < 4; ++r4) pv[r4] = 0.f;
#pragma unroll 2
    for (int i = 0; i < 24; ++i){
      int r = r0 + i;
      f32x4 a0 = {0,0,0,0};
#pragma unroll
      for (int dh = 0; dh < 3; ++dh)
#pragma unroll
        for (int dw = 0; dw < 3; ++dw)
#pragma unroll
          for (int hf = 0; hf < 2; ++hf){
            bf16x8 bf = *reinterpret_cast<const bf16x8*>(h2a + (((r+dh)*8 + hf*4 + kq)*13 + px + dw)*8);
            a0 = MFMA16(wt[(dh*3+dw)*2 + hf], bf, a0);
          }
      if ((i & 1) == 0){
#pragma unroll
        for (int r4 = 0; r4 < 4; ++r4) pv[r4] = rb(a0[r4], bt[r4]);
      } else {
        if (r16 < 11){
          int pp = (r >> 1)*11 + px;
          unsigned short* dp = P2g + (size_t)s*16896 + pp*64 + ct*16 + kq*4;
          u32x2 qv;
          float c0, c1;
          c0 = rb(a0[0], bt[0]); c1 = rb(a0[1], bt[1]);
          qv.x = pack2(pv[0] > c0 ? pv[0] : c0, pv[1] > c1 ? pv[1] : c1);
          c0 = rb(a0[2], bt[2]); c1 = rb(a0[3], bt[3]);
          qv.y = pack2(pv[2] > c0 ? pv[2] : c0, pv[3] > c1 ? pv[3] : c1);
          *reinterpret_cast<u32x2*>(dp) = qv;
        }
      }
    }
  }
}

// ---------------- conv3 (64->128, 12x9) + relu + sum(13x3) + 1x1 head, 4 samples/block
// waves = (tg: co-half) x (sg: sample-pair) x (par: kb parity); par-reduction via LDS
__global__ __launch_bounds__(512)
__attribute__((amdgpu_waves_per_eu(2, 2)))
void conv3_k(const unsigned short* __restrict__ p2,
      const unsigned short* __restrict__ wp3, const float* __restrict__ b3,
      const float* __restrict__ wl, const float* __restrict__ bl,
      float* __restrict__ out)
{
  __shared__ __align__(16) char smem[137216];
  char* lds = smem;                                   // 4 * 33792 staged P2 (swizzled); later reduction
  float* sbuf = (float*)(smem + 135168);              // 4 * 128 floats

  const int tid = threadIdx.x;
  const int lane = tid & 63, wid = tid >> 6;
  const int r16 = lane & 15, kq = lane >> 4;
  const int blk = blockIdx.x;

  // stage 4 samples, XOR-swizzled channel-quads
  const unsigned short* src = p2 + (size_t)blk * 4 * 16896;
  for (int c = tid; c < 8448; c += 512){
    int e = c * 8;
    int sl = e / 16896; int er = e - sl * 16896;
    int pix = er >> 6; int cc = (er >> 3) & 7;
    int dstb = sl * 33792 + pix * 128 + ((cc ^ (pix & 7)) << 4);
    *reinterpret_cast<bf16x8*>(lds + dstb) = ld16u(src + e);
  }
  __syncthreads();

  const int tg = wid & 1, sg = (wid >> 1) & 1, par = wid >> 2;
  int ipb[3]; int vm[3];
#pragma unroll
  for (int m = 0; m < 3; ++m){
    int p = m*16 + r16;
    vm[m] = (p < 39);
    int pc = p < 39 ? p : 38;
    int h = pc / 3, w = pc - h*3;
    ipb[m] = h*11 + w;
  }
  f32x4 acc[3][2][4];
#pragma unroll
  for (int m = 0; m < 3; ++m)
#pragma unroll
    for (int ss2 = 0; ss2 < 2; ++ss2)
#pragma unroll
      for (int t4 = 0; t4 < 4; ++t4) acc[m][ss2][t4] = (f32x4){0,0,0,0};

  const unsigned short* wb = wp3 + (size_t)par*4096 + tg*2048 + r16*32 + kq*8;
  bf16x8 wc[4];
#pragma unroll
  for (int t4 = 0; t4 < 4; ++t4) wc[t4] = ld16u(wb + t4*512);
  const int cc0 = par*4 + kq;
  int dh = 0, dw = 0;
  for (int k = 0; k < 108; ++k){
    bf16x8 wn[4];
    if (k < 107){
      const unsigned short* wb2 = wb + (size_t)(k+1)*8192;
#pragma unroll
      for (int t4 = 0; t4 < 4; ++t4) wn[t4] = ld16u(wb2 + t4*512);
    } else {
#pragma unroll
      for (int t4 = 0; t4 < 4; ++t4) wn[t4] = wc[t4];
    }
    int d = dh*11 + dw;
#pragma unroll
    for (int m = 0; m < 3; ++m){
      int ip = ipb[m] + d;
      int bo = ip*128 + ((cc0 ^ (ip & 7)) << 4);
#pragma unroll
      for (int ss2 = 0; ss2 < 2; ++ss2){
        bf16x8 bf = *reinterpret_cast<const bf16x8*>(lds + (sg*2 + ss2)*33792 + bo);
#pragma unroll
        for (int t4 = 0; t4 < 4; ++t4) acc[m][ss2][t4] = MFMA16(wc[t4], bf, acc[m][ss2][t4]);
      }
    }
#pragma unroll
    for (int t4 = 0; t4 < 4; ++t4) wc[t4] = wn[t4];
    if (++dw == 9){ dw = 0; ++dh; }
  }
  __syncthreads();

  f32x4* red = (f32x4*)lds;   // 4 waves * 24 * 64 * 16B = 98304 <= 135168
  if (par == 1){
#pragma unroll
    for (int m = 0; m < 3; ++m)
#pragma unroll
      for (int ss2 = 0; ss2 < 2; ++ss2)
#pragma unroll
        for (int t4 = 0; t4 < 4; ++t4)
          red[(((tg*2 + sg)*6 + m*2 + ss2)*4 + t4)*64 + lane] = acc[m][ss2][t4];
  }
  __syncthreads();
  if (par == 0){
    float sv[2][4][4];
#pragma unroll
    for (int m = 0; m < 3; ++m)
#pragma unroll
      for (int ss2 = 0; ss2 < 2; ++ss2)
#pragma unroll
        for (int t4 = 0; t4 < 4; ++t4){
          f32x4 o = red[(((tg*2 + sg)*6 + m*2 + ss2)*4 + t4)*64 + lane];
#pragma unroll
          for (int r = 0; r < 4; ++r){
            float v = acc[m][ss2][t4][r] + o[r] + b3[(tg*4 + t4)*16 + kq*4 + r];
            v = v > 0.f ? v : 0.f;
            v = vm[m] ? v : 0.f;
            if (m == 0) sv[ss2][t4][r] = v; else sv[ss2][t4][r] += v;
          }
        }
#pragma unroll
    for (int off = 1; off < 16; off <<= 1)
#pragma unroll
      for (int ss2 = 0; ss2 < 2; ++ss2)
#pragma unroll
        for (int t4 = 0; t4 < 4; ++t4)
#pragma unroll
          for (int r = 0; r < 4; ++r) sv[ss2][t4][r] += __shfl_xor(sv[ss2][t4][r], off, 16);
    if (r16 == 0){
#pragma unroll
      for (int ss2 = 0; ss2 < 2; ++ss2)
#pragma unroll
        for (int t4 = 0; t4 < 4; ++t4)
#pragma unroll
          for (int r = 0; r < 4; ++r)
            sbuf[(sg*2 + ss2)*128 + (tg*4 + t4)*16 + kq*4 + r] = sv[ss2][t4][r];
    }
  }
  __syncthreads();
  if (tid < 100){
    int ss = tid / 25, o = tid - ss*25;
    float a = 0.f;
    for (int c = 0; c < 128; ++c) a += wl[o*128 + c] * sbuf[ss*128 + c];
    out[(size_t)(blk*4 + ss)*25 + o] = a * (1.f/39.f) + bl[o];
  }
}

extern "C" void kernel_launch(void* const* d_in, const int* in_sizes, int n_in,
                              void* d_out, int out_size, void* d_ws, size_t ws_size,
                              hipStream_t stream){
  const float* x   = (const float*)d_in[0];
  const float* w1a = (const float*)d_in[1];  const float* b1a = (const float*)d_in[2];
  const float* w1b = (const float*)d_in[3];  const float* b1b = (const float*)d_in[4];
  const float* w1c = (const float*)d_in[5];  const float* b1c = (const float*)d_in[6];
  const float* w1d = (const float*)d_in[7];  const float* b1d = (const float*)d_in[8];
  const float* w2a = (const float*)d_in[9];  const float* b2a = (const float*)d_in[10];
  const float* w2b = (const float*)d_in[11]; const float* b2b = (const float*)d_in[12];
  const float* w3  = (const float*)d_in[13]; const float* b3  = (const float*)d_in[14];
  const float* wl  = (const float*)d_in[15]; const float* bl  = (const float*)d_in[16];
  float* out = (float*)d_out;

  unsigned short* ws0  = (unsigned short*)d_ws;
  unsigned short* wp1a = ws0;                 // 1024 (hi/lo split)
  unsigned short* wp1b = wp1a + 1024;         // 9216
  unsigned short* wp1c = wp1b + 9216;         // 9216
  unsigned short* wp1d = wp1c + 9216;         // 9216
  unsigned short* wp2a = wp1d + 9216;         // 18432
  unsigned short* wp2b = wp2a + 18432;        // 36864
  unsigned short* wp3  = wp2b + 36864;        // 884736
  unsigned short* P2   = wp3 + 884736;        // 2048 * 16896

  pack_w1a<<<4, 256, 0, stream>>>(w1a, wp1a);
  pack_w<<<36,   256, 0, stream>>>(w1b, wp1b, 32, 32, 3, 3);
  pack_w<<<36,   256, 0, stream>>>(w1c, wp1c, 32, 32, 3, 3);
  pack_w<<<36,   256, 0, stream>>>(w1d, wp1d, 32, 32, 3, 3);
  pack_w<<<72,   256, 0, stream>>>(w2a, wp2a, 64, 32, 3, 3);
  pack_w<<<144,  256, 0, stream>>>(w2b, wp2b, 64, 64, 3, 3);
  pack_w<<<3456, 256, 0, stream>>>(w3,  wp3, 128, 64, 12, 9);

  fused_k<<<2048, 512, 0, stream>>>(x, wp1a, b1a, wp1b, b1b, wp1c, b1c, wp1d, b1d,
                                    wp2a, b2a, wp2b, b2b, P2);
  conv3_k<<<512, 512, 0, stream>>>(P2, wp3, b3, wl, bl, out);
}